// Round 1
// baseline (2172.134 us; speedup 1.0000x reference)
//
#include <hip/hip_runtime.h>
#include <stdint.h>

#define NTOK 4096
#define HDIM 2048
#define IDIM 5632
#define NEXP 8
#define NSLOT 8192   // NTOK * K, exact (every token appears in exactly 2 expert lists)

typedef __attribute__((ext_vector_type(8))) __bf16 bf16x8;
typedef __attribute__((ext_vector_type(4))) float f32x4;

__device__ __forceinline__ unsigned short f2bf(float f) {
  union { float f; unsigned int u; } a; a.f = f;
  unsigned int r = a.u + 0x7FFFu + ((a.u >> 16) & 1u);   // RNE
  return (unsigned short)(r >> 16);
}
__device__ __forceinline__ float bf2f(unsigned short h) {
  union { unsigned int u; float f; } a; a.u = ((unsigned int)h) << 16;
  return a.f;
}
// Swizzled LDS tile: 128 rows x 8 chunks of 8 bf16 (16B). XOR swizzle keeps both
// staging writes and MFMA fragment reads at <=2-way bank aliasing (free, m136).
__device__ __forceinline__ int lds_off(int r, int c) {
  return r * 64 + (((c ^ (r & 7))) << 3);   // in bf16 elements
}

// ---------- fp32 -> bf16 bulk convert (8 elts / thread) ----------
__global__ __launch_bounds__(256) void cvt_kernel(const float* __restrict__ src,
                                                  unsigned short* __restrict__ dst, int n8) {
  int i = blockIdx.x * 256 + threadIdx.x;
  if (i >= n8) return;
  const float4* p = (const float4*)src + (size_t)i * 2;
  float4 a = p[0], b = p[1];
  uint4 v;
  v.x = (unsigned)f2bf(a.x) | ((unsigned)f2bf(a.y) << 16);
  v.y = (unsigned)f2bf(a.z) | ((unsigned)f2bf(a.w) << 16);
  v.z = (unsigned)f2bf(b.x) | ((unsigned)f2bf(b.y) << 16);
  v.w = (unsigned)f2bf(b.z) | ((unsigned)f2bf(b.w) << 16);
  ((uint4*)dst)[i] = v;
}

// ---------- router: fp32 logits, softmax, top-2 (exact selection) ----------
__global__ __launch_bounds__(64) void router_kernel(const float* __restrict__ x,
                                                    const float* __restrict__ rw,
                                                    int* __restrict__ topk_idx,
                                                    float* __restrict__ topk_w,
                                                    int* __restrict__ counts) {
  int t = blockIdx.x;
  int lane = threadIdx.x;
  const float* xr = x + (size_t)t * HDIM;
  float xv[32];
#pragma unroll
  for (int i = 0; i < 32; ++i) xv[i] = xr[i * 64 + lane];
  __shared__ float lg[NEXP];
#pragma unroll
  for (int e = 0; e < NEXP; ++e) {
    const float* w = rw + e * HDIM;
    float s = 0.f;
#pragma unroll
    for (int i = 0; i < 32; ++i) s += xv[i] * w[i * 64 + lane];
#pragma unroll
    for (int off = 32; off > 0; off >>= 1) s += __shfl_down(s, off);
    if (lane == 0) lg[e] = s;
  }
  __syncthreads();
  if (lane == 0) {
    float mx = lg[0];
    for (int e = 1; e < NEXP; ++e) mx = fmaxf(mx, lg[e]);
    float p[NEXP], se = 0.f;
    for (int e = 0; e < NEXP; ++e) { p[e] = __expf(lg[e] - mx); se += p[e]; }
    float inv = 1.f / se;
    int i1 = 0; float b1 = lg[0];                 // strict > : ties -> lowest index (matches lax.top_k)
    for (int e = 1; e < NEXP; ++e) if (lg[e] > b1) { b1 = lg[e]; i1 = e; }
    int i2 = -1; float b2 = -__builtin_inff();
    for (int e = 0; e < NEXP; ++e) if (e != i1 && lg[e] > b2) { b2 = lg[e]; i2 = e; }
    topk_idx[t * 2 + 0] = i1;
    topk_idx[t * 2 + 1] = i2;
    topk_w[t * 2 + 0] = p[i1] * inv;              // softmax probs, NOT renormalized
    topk_w[t * 2 + 1] = p[i2] * inv;
    atomicAdd(&counts[i1], 1);
    atomicAdd(&counts[i2], 1);
  }
}

__global__ void scan_kernel(const int* __restrict__ counts, int* __restrict__ offsets) {
  if (threadIdx.x == 0 && blockIdx.x == 0) {
    int acc = 0;
    for (int e = 0; e < NEXP; ++e) { offsets[e] = acc; acc += counts[e]; }
    offsets[NEXP] = acc;
  }
}

__global__ __launch_bounds__(256) void fill_kernel(const int* __restrict__ topk_idx,
                                                   const int* __restrict__ offsets,
                                                   int* __restrict__ fillc,
                                                   int* __restrict__ rowsbuf,
                                                   int* __restrict__ slotmap) {
  int t = blockIdx.x * 256 + threadIdx.x;
  if (t >= NTOK) return;
#pragma unroll
  for (int k = 0; k < 2; ++k) {
    int e = topk_idx[t * 2 + k];
    int pos = atomicAdd(&fillc[e], 1);
    int slot = offsets[e] + pos;
    rowsbuf[slot] = t;
    slotmap[t * 2 + k] = slot;
  }
}

// ---------- fused gate+up GEMM + silu*mul, bf16 MFMA ----------
// grid (IDIM/128, 32, NEXP), 256 threads (4 waves, 2x2), early-exit on m-tile.
__global__ __launch_bounds__(256, 2) void gateup_kernel(
    const unsigned short* __restrict__ xb,
    const unsigned short* __restrict__ wgall,   // bf16 [E][I][H]
    const unsigned short* __restrict__ wuall,   // bf16 [E][I][H]
    const int* __restrict__ offsets,
    const int* __restrict__ rowsbuf,
    unsigned short* __restrict__ hbuf) {        // bf16 [NSLOT][I]
  int e = blockIdx.z;
  int off0 = offsets[e];
  int cnt = offsets[e + 1] - off0;
  int m0 = blockIdx.y * 128;
  if (m0 >= cnt) return;
  int n0 = blockIdx.x * 128;
  int tid = threadIdx.x;
  const unsigned short* wg = wgall + (size_t)e * IDIM * HDIM;
  const unsigned short* wu = wuall + (size_t)e * IDIM * HDIM;

  __shared__ unsigned short As[8192], Bg[8192], Bu[8192];
  __shared__ int toks[128];
  if (tid < 128) {
    int r = (m0 + tid < cnt) ? tid : 0;         // pad rows duplicate row 0 (never stored)
    toks[tid] = rowsbuf[off0 + m0 + r];
  }
  __syncthreads();

  // per-thread staging geometry (4 chunks of 16B per matrix)
  int tokr[4], ldso[4];
  const unsigned short* aptr[4];
  const unsigned short* gptr[4];
  const unsigned short* uptr[4];
#pragma unroll
  for (int i = 0; i < 4; ++i) {
    int ch = tid + i * 256;
    int r = ch >> 3, c = ch & 7;
    tokr[i] = toks[r];
    ldso[i] = lds_off(r, c);
    aptr[i] = xb + (size_t)tokr[i] * HDIM + c * 8;
    gptr[i] = wg + (size_t)(n0 + r) * HDIM + c * 8;
    uptr[i] = wu + (size_t)(n0 + r) * HDIM + c * 8;
  }

  f32x4 accg[4][4], accu[4][4];
  f32x4 zero = {0.f, 0.f, 0.f, 0.f};
#pragma unroll
  for (int a = 0; a < 4; ++a)
#pragma unroll
    for (int b = 0; b < 4; ++b) { accg[a][b] = zero; accu[a][b] = zero; }

  int lane = tid & 63, wid = tid >> 6;
  int wm = wid >> 1, wn = wid & 1;
  int quad = lane >> 4, l16 = lane & 15;

  for (int kt = 0; kt < HDIM / 64; ++kt) {
    int kbase = kt * 64;
#pragma unroll
    for (int i = 0; i < 4; ++i) {
      *(uint4*)&As[ldso[i]] = *(const uint4*)(aptr[i] + kbase);
      *(uint4*)&Bg[ldso[i]] = *(const uint4*)(gptr[i] + kbase);
      *(uint4*)&Bu[ldso[i]] = *(const uint4*)(uptr[i] + kbase);
    }
    __syncthreads();
#pragma unroll
    for (int kk = 0; kk < 2; ++kk) {
      int kg = kk * 4 + quad;
      bf16x8 af[4], bgf[4], buf_[4];
#pragma unroll
      for (int mi = 0; mi < 4; ++mi) {
        int r = wm * 64 + mi * 16 + l16;
        af[mi] = *(const bf16x8*)&As[lds_off(r, kg)];
      }
#pragma unroll
      for (int ni = 0; ni < 4; ++ni) {
        int r = wn * 64 + ni * 16 + l16;
        int o = lds_off(r, kg);
        bgf[ni] = *(const bf16x8*)&Bg[o];
        buf_[ni] = *(const bf16x8*)&Bu[o];
      }
#pragma unroll
      for (int mi = 0; mi < 4; ++mi)
#pragma unroll
        for (int ni = 0; ni < 4; ++ni) {
          accg[mi][ni] = __builtin_amdgcn_mfma_f32_16x16x32_bf16(af[mi], bgf[ni], accg[mi][ni], 0, 0, 0);
          accu[mi][ni] = __builtin_amdgcn_mfma_f32_16x16x32_bf16(af[mi], buf_[ni], accu[mi][ni], 0, 0, 0);
        }
    }
    __syncthreads();
  }
  // epilogue: h = silu(g)*u -> bf16.  C/D layout: col=lane&15, row=quad*4+reg (m89)
#pragma unroll
  for (int mi = 0; mi < 4; ++mi)
#pragma unroll
    for (int ni = 0; ni < 4; ++ni) {
      f32x4 g = accg[mi][ni], u = accu[mi][ni];
      int col = n0 + wn * 64 + ni * 16 + l16;
#pragma unroll
      for (int r4 = 0; r4 < 4; ++r4) {
        int m = wm * 64 + mi * 16 + quad * 4 + r4;
        if (m0 + m < cnt) {
          float gv = g[r4], uv = u[r4];
          float hv = gv / (1.f + __expf(-gv)) * uv;
          hbuf[(size_t)(off0 + m0 + m) * IDIM + col] = f2bf(hv);
        }
      }
    }
}

// ---------- down GEMM: y = h @ down_w[e].T (unweighted), bf16 out ----------
__global__ __launch_bounds__(256, 2) void down_kernel(
    const unsigned short* __restrict__ hbuf,    // bf16 [NSLOT][I]
    const unsigned short* __restrict__ wdall,   // bf16 [E][H][I]
    const int* __restrict__ offsets,
    unsigned short* __restrict__ ybuf) {        // bf16 [NSLOT][H]
  int e = blockIdx.z;
  int off0 = offsets[e];
  int cnt = offsets[e + 1] - off0;
  int m0 = blockIdx.y * 128;
  if (m0 >= cnt) return;
  int n0 = blockIdx.x * 128;
  int tid = threadIdx.x;
  const unsigned short* wd = wdall + (size_t)e * HDIM * IDIM;

  __shared__ unsigned short As[8192], Bs[8192];

  int ldso[4];
  const unsigned short* aptr[4];
  const unsigned short* bptr[4];
#pragma unroll
  for (int i = 0; i < 4; ++i) {
    int ch = tid + i * 256;
    int r = ch >> 3, c = ch & 7;
    int rr = (m0 + r < cnt) ? r : 0;            // clamp: stay inside hbuf
    ldso[i] = lds_off(r, c);
    aptr[i] = hbuf + (size_t)(off0 + m0 + rr) * IDIM + c * 8;
    bptr[i] = wd + (size_t)(n0 + r) * IDIM + c * 8;
  }

  f32x4 acc[4][4];
  f32x4 zero = {0.f, 0.f, 0.f, 0.f};
#pragma unroll
  for (int a = 0; a < 4; ++a)
#pragma unroll
    for (int b = 0; b < 4; ++b) acc[a][b] = zero;

  int lane = tid & 63, wid = tid >> 6;
  int wm = wid >> 1, wn = wid & 1;
  int quad = lane >> 4, l16 = lane & 15;

  for (int kt = 0; kt < IDIM / 64; ++kt) {
    int kbase = kt * 64;
#pragma unroll
    for (int i = 0; i < 4; ++i) {
      *(uint4*)&As[ldso[i]] = *(const uint4*)(aptr[i] + kbase);
      *(uint4*)&Bs[ldso[i]] = *(const uint4*)(bptr[i] + kbase);
    }
    __syncthreads();
#pragma unroll
    for (int kk = 0; kk < 2; ++kk) {
      int kg = kk * 4 + quad;
      bf16x8 af[4], bf[4];
#pragma unroll
      for (int mi = 0; mi < 4; ++mi)
        af[mi] = *(const bf16x8*)&As[lds_off(wm * 64 + mi * 16 + l16, kg)];
#pragma unroll
      for (int ni = 0; ni < 4; ++ni)
        bf[ni] = *(const bf16x8*)&Bs[lds_off(wn * 64 + ni * 16 + l16, kg)];
#pragma unroll
      for (int mi = 0; mi < 4; ++mi)
#pragma unroll
        for (int ni = 0; ni < 4; ++ni)
          acc[mi][ni] = __builtin_amdgcn_mfma_f32_16x16x32_bf16(af[mi], bf[ni], acc[mi][ni], 0, 0, 0);
    }
    __syncthreads();
  }
#pragma unroll
  for (int mi = 0; mi < 4; ++mi)
#pragma unroll
    for (int ni = 0; ni < 4; ++ni) {
      f32x4 y = acc[mi][ni];
      int col = n0 + wn * 64 + ni * 16 + l16;
#pragma unroll
      for (int r4 = 0; r4 < 4; ++r4) {
        int m = wm * 64 + mi * 16 + quad * 4 + r4;
        if (m0 + m < cnt)
          ybuf[(size_t)(off0 + m0 + m) * HDIM + col] = f2bf(y[r4]);
      }
    }
}

// ---------- gather: out[t] = w0*y[slot0] + w1*y[slot1] (fp32 out) ----------
__global__ __launch_bounds__(256) void gather_kernel(const unsigned short* __restrict__ ybuf,
                                                     const int* __restrict__ slotmap,
                                                     const float* __restrict__ topk_w,
                                                     float* __restrict__ out) {
  int t = blockIdx.x;
  int tid = threadIdx.x;
  int s0 = slotmap[t * 2 + 0], s1 = slotmap[t * 2 + 1];
  float w0 = topk_w[t * 2 + 0], w1 = topk_w[t * 2 + 1];
  int c = tid * 8;
  uint4 a = *(const uint4*)(ybuf + (size_t)s0 * HDIM + c);
  uint4 b = *(const uint4*)(ybuf + (size_t)s1 * HDIM + c);
  float fa[8], fb[8];
  fa[0]=bf2f(a.x&0xffff); fa[1]=bf2f(a.x>>16); fa[2]=bf2f(a.y&0xffff); fa[3]=bf2f(a.y>>16);
  fa[4]=bf2f(a.z&0xffff); fa[5]=bf2f(a.z>>16); fa[6]=bf2f(a.w&0xffff); fa[7]=bf2f(a.w>>16);
  fb[0]=bf2f(b.x&0xffff); fb[1]=bf2f(b.x>>16); fb[2]=bf2f(b.y&0xffff); fb[3]=bf2f(b.y>>16);
  fb[4]=bf2f(b.z&0xffff); fb[5]=bf2f(b.z>>16); fb[6]=bf2f(b.w&0xffff); fb[7]=bf2f(b.w>>16);
  float4 o0, o1;
  o0.x = w0*fa[0]+w1*fb[0]; o0.y = w0*fa[1]+w1*fb[1];
  o0.z = w0*fa[2]+w1*fb[2]; o0.w = w0*fa[3]+w1*fb[3];
  o1.x = w0*fa[4]+w1*fb[4]; o1.y = w0*fa[5]+w1*fb[5];
  o1.z = w0*fa[6]+w1*fb[6]; o1.w = w0*fa[7]+w1*fb[7];
  float* op = out + (size_t)t * HDIM + c;
  *(float4*)op = o0;
  *(float4*)(op + 4) = o1;
}

extern "C" void kernel_launch(void* const* d_in, const int* in_sizes, int n_in,
                              void* d_out, int out_size, void* d_ws, size_t ws_size,
                              hipStream_t stream) {
  const float* x  = (const float*)d_in[0];
  const float* rw = (const float*)d_in[1];
  const float* gw = (const float*)d_in[2];
  const float* uw = (const float*)d_in[3];
  const float* dw = (const float*)d_in[4];
  float* out = (float*)d_out;
  char* ws = (char*)d_ws;

  // workspace layout (≈488 MiB total)
  int*   counts   = (int*)(ws + 0);
  int*   fillc    = (int*)(ws + 32);
  int*   offsets  = (int*)(ws + 64);
  int*   topk_idx = (int*)(ws + 128);
  float* topk_w   = (float*)(ws + 32896);
  int*   slotmap  = (int*)(ws + 65664);
  int*   rowsbuf  = (int*)(ws + 98432);
  unsigned short* xb   = (unsigned short*)(ws + 131328);
  unsigned short* hbuf = (unsigned short*)(ws + 131328 + (size_t)NTOK * HDIM * 2);
  unsigned short* ybuf = (unsigned short*)((char*)hbuf + (size_t)NSLOT * IDIM * 2);
  unsigned short* wgb  = (unsigned short*)((char*)ybuf + (size_t)NSLOT * HDIM * 2);
  unsigned short* wub  = wgb + (size_t)NEXP * IDIM * HDIM;
  unsigned short* wdb  = wgb;   // down reuses gate region (stream-ordered)

  hipMemsetAsync(ws, 0, 128, stream);

  cvt_kernel<<<NTOK * HDIM / 8 / 256, 256, 0, stream>>>(x, xb, NTOK * HDIM / 8);
  router_kernel<<<NTOK, 64, 0, stream>>>(x, rw, topk_idx, topk_w, counts);
  scan_kernel<<<1, 64, 0, stream>>>(counts, offsets);
  fill_kernel<<<NTOK / 256, 256, 0, stream>>>(topk_idx, offsets, fillc, rowsbuf, slotmap);

  const int wn8 = NEXP * IDIM * HDIM / 8;
  cvt_kernel<<<(wn8 + 255) / 256, 256, 0, stream>>>(gw, wgb, wn8);
  cvt_kernel<<<(wn8 + 255) / 256, 256, 0, stream>>>(uw, wub, wn8);
  gateup_kernel<<<dim3(IDIM / 128, NTOK / 128, NEXP), 256, 0, stream>>>(
      xb, wgb, wub, offsets, rowsbuf, hbuf);
  cvt_kernel<<<(wn8 + 255) / 256, 256, 0, stream>>>(dw, wdb, wn8);
  down_kernel<<<dim3(HDIM / 128, NTOK / 128, NEXP), 256, 0, stream>>>(
      hbuf, wdb, offsets, ybuf);
  gather_kernel<<<NTOK, 256, 0, stream>>>(ybuf, slotmap, topk_w, out);
}